// Round 2
// baseline (175.322 us; speedup 1.0000x reference)
//
#include <hip/hip_runtime.h>

#define BB 16
#define LL 2048
#define DD 768
#define KK 32
#define NEGI -1e30f
#define JJ 4                 // sub-blocks per span (split-J)
#define AW 4                 // waves per A-block
#define SLOTS (JJ * AW)      // 16 row-slots per span

// Phase A: grid (B*K, J). Each block = 4 waves; wave handles rows
// l = s0 + (j*AW + wave) + i*16 of span bk. Online-softmax state in
// registers with DEFER-RESCALE: after the cross-lane reduce d is
// wave-uniform, so the d<=m test is a uniform branch; the common path
// (not a new max) is 12 FMA + 1 exp, and the rare new-max path is ALSO
// 12 FMA + 1 exp (acc = acc*sc + r, e==1). This is an exact algebraic
// reordering of the previous unconditional-rescale update (24 FMA +
// 2 exp + fmax per row) — same numerics, ~40% less VALU.
// JJ=4 (was 8): average span is ~60 rows, so J=8 blocks mostly ran <2
// rows/wave of real work; J=4 halves block prologue/epilogue overhead
// and phase-B partial traffic while keeping the worst sub-span ~19
// rows/wave (~2 µs). No cross-workgroup sync anywhere.
__global__ __launch_bounds__(256) void span_pool_a(
    const float* __restrict__ th,
    const float* __restrict__ attn,
    const int* __restrict__ sps,
    const int* __restrict__ spe,
    const float* __restrict__ wp,
    float* __restrict__ pacc,   // [B*K, J, 768] unnormalized
    float* __restrict__ pm,     // [B*K, J] running max
    float* __restrict__ ps) {   // [B*K, J] running sum
  const int bk = blockIdx.x;          // b*K + k
  const int j  = blockIdx.y;          // sub-block within span
  const int b  = bk >> 5;             // K = 32
  const int lane = threadIdx.x & 63;
  const int wave = threadIdx.x >> 6;
  const int slot = j * AW + wave;     // 0..15

  __shared__ float sacc[AW][DD];      // 12 KB wave-partial accumulators
  __shared__ float sm[AW], ss[AW];

  int s0 = min(max(sps[bk], 0), LL);
  int e0 = min(max(spe[bk], 0), LL);

  // pooling weights: lane owns dims {4*lane, 256+4*lane, 512+4*lane}+[0,3]
  const float4* wr = (const float4*)wp;
  const float4 w0 = wr[lane], w1 = wr[lane + 64], w2 = wr[lane + 128];

  const float* arow = attn + (size_t)b * LL;
  const float4* tb = (const float4*)(th + (size_t)b * LL * DD);

  float m = NEGI, s = 0.f;
  float4 a0 = make_float4(0.f, 0.f, 0.f, 0.f), a1 = a0, a2 = a0;

  #pragma unroll 2
  for (int l = s0 + slot; l < e0; l += SLOTS) {
    const float4* row = tb + (size_t)l * (DD / 4);
    float4 r0 = row[lane], r1 = row[lane + 64], r2 = row[lane + 128];
    float am = arow[l];  // lane-uniform broadcast load

    float d = 0.f;
    d = fmaf(r0.x, w0.x, d); d = fmaf(r0.y, w0.y, d);
    d = fmaf(r0.z, w0.z, d); d = fmaf(r0.w, w0.w, d);
    d = fmaf(r1.x, w1.x, d); d = fmaf(r1.y, w1.y, d);
    d = fmaf(r1.z, w1.z, d); d = fmaf(r1.w, w1.w, d);
    d = fmaf(r2.x, w2.x, d); d = fmaf(r2.y, w2.y, d);
    d = fmaf(r2.z, w2.z, d); d = fmaf(r2.w, w2.w, d);
    #pragma unroll
    for (int o = 32; o > 0; o >>= 1) d += __shfl_xor(d, o, 64);

    if (am >= 0.5f) {       // wave-uniform (am identical across lanes)
      if (d <= m) {         // wave-uniform (d uniform after reduce)
        const float e = __expf(d - m);
        s += e;
        a0.x = fmaf(e, r0.x, a0.x); a0.y = fmaf(e, r0.y, a0.y);
        a0.z = fmaf(e, r0.z, a0.z); a0.w = fmaf(e, r0.w, a0.w);
        a1.x = fmaf(e, r1.x, a1.x); a1.y = fmaf(e, r1.y, a1.y);
        a1.z = fmaf(e, r1.z, a1.z); a1.w = fmaf(e, r1.w, a1.w);
        a2.x = fmaf(e, r2.x, a2.x); a2.y = fmaf(e, r2.y, a2.y);
        a2.z = fmaf(e, r2.z, a2.z); a2.w = fmaf(e, r2.w, a2.w);
      } else {              // new max: e == 1, rescale old state
        const float sc = __expf(m - d);  // first valid row: exp(-huge)=0
        s = fmaf(s, sc, 1.0f);
        a0.x = fmaf(a0.x, sc, r0.x); a0.y = fmaf(a0.y, sc, r0.y);
        a0.z = fmaf(a0.z, sc, r0.z); a0.w = fmaf(a0.w, sc, r0.w);
        a1.x = fmaf(a1.x, sc, r1.x); a1.y = fmaf(a1.y, sc, r1.y);
        a1.z = fmaf(a1.z, sc, r1.z); a1.w = fmaf(a1.w, sc, r1.w);
        a2.x = fmaf(a2.x, sc, r2.x); a2.y = fmaf(a2.y, sc, r2.y);
        a2.z = fmaf(a2.z, sc, r2.z); a2.w = fmaf(a2.w, sc, r2.w);
        m = d;
      }
    }
  }

  // publish wave partials
  float4* sa = (float4*)sacc[wave];
  sa[lane] = a0; sa[lane + 64] = a1; sa[lane + 128] = a2;
  if (lane == 0) { sm[wave] = m; ss[wave] = s; }
  __syncthreads();

  // merge 4 wave-partials into one UNNORMALIZED (M, S, acc) partial.
  // Every (bk,j) writes all 770 values unconditionally — workspace is
  // poisoned between iterations, B must never read stale bytes.
  const int t = threadIdx.x;
  if (t < DD / 4) {
    float M = NEGI;
    #pragma unroll
    for (int w = 0; w < AW; ++w) M = fmaxf(M, sm[w]);
    float S = 0.f;
    float4 o = make_float4(0.f, 0.f, 0.f, 0.f);
    #pragma unroll
    for (int w = 0; w < AW; ++w) {
      const float ew = __expf(sm[w] - M);  // empty wave: s=0, acc=0 -> no-op
      S = fmaf(ew, ss[w], S);
      const float4 p = ((const float4*)sacc[w])[t];
      o.x = fmaf(ew, p.x, o.x); o.y = fmaf(ew, p.y, o.y);
      o.z = fmaf(ew, p.z, o.z); o.w = fmaf(ew, p.w, o.w);
    }
    ((float4*)(pacc + (size_t)(bk * JJ + j) * DD))[t] = o;
    if (t == 0) { pm[bk * JJ + j] = M; ps[bk * JJ + j] = S; }
  }
}

// Phase B: one 192-thread block per (b,k). Merge the J=4 partials
// (6.3 MB total read, mostly L2-warm), normalize, write H + sent.
__global__ __launch_bounds__(192) void span_pool_b(
    const float* __restrict__ pacc,
    const float* __restrict__ pm,
    const float* __restrict__ ps,
    float* __restrict__ Hout,
    float* __restrict__ sent) {
  const int bk = blockIdx.x;
  const int t = threadIdx.x;  // 0..191, one float4 of the 768 dims each

  float mj[JJ], sj[JJ];
  float M = NEGI;
  #pragma unroll
  for (int jv = 0; jv < JJ; ++jv) {
    mj[jv] = pm[bk * JJ + jv];
    sj[jv] = ps[bk * JJ + jv];
    M = fmaxf(M, mj[jv]);
  }
  float S = 0.f;
  #pragma unroll
  for (int jv = 0; jv < JJ; ++jv) S = fmaf(__expf(mj[jv] - M), sj[jv], S);
  const float inv = (S > 0.f) ? (1.0f / S) : 0.f;  // empty/all-masked -> 0

  float4 o = make_float4(0.f, 0.f, 0.f, 0.f);
  #pragma unroll
  for (int jv = 0; jv < JJ; ++jv) {
    const float ew = __expf(mj[jv] - M);  // empty partial: exp->0 or acc=0
    const float4 p = ((const float4*)(pacc + (size_t)(bk * JJ + jv) * DD))[t];
    o.x = fmaf(ew, p.x, o.x); o.y = fmaf(ew, p.y, o.y);
    o.z = fmaf(ew, p.z, o.z); o.w = fmaf(ew, p.w, o.w);
  }
  o.x *= inv; o.y *= inv; o.z *= inv; o.w *= inv;
  ((float4*)(Hout + (size_t)bk * DD))[t] = o;  // all 768 dims always written
  if (t == 0) sent[bk] = (S > 0.f) ? 1.0f : 0.0f;
}

extern "C" void kernel_launch(void* const* d_in, const int* in_sizes, int n_in,
                              void* d_out, int out_size, void* d_ws, size_t ws_size,
                              hipStream_t stream) {
  const float* th   = (const float*)d_in[0];  // [B,L,D] fp32
  const float* attn = (const float*)d_in[1];  // [B,L]   fp32
  const int*   sps  = (const int*)d_in[2];    // [B,K]
  const int*   spe  = (const int*)d_in[3];    // [B,K]
  const float* wp   = (const float*)d_in[4];  // [D]     fp32
  // d_in[5] (b_pool) intentionally unused: softmax(x + c) == softmax(x)

  float* Hout = (float*)d_out;                 // [B,K,D] then sent [B,K]
  float* sent = Hout + (size_t)BB * KK * DD;

  // workspace: 512*4*768 + 2*512*4 floats = 6.3 MB (ws is ~384 MB)
  float* pacc = (float*)d_ws;
  float* pm   = pacc + (size_t)BB * KK * JJ * DD;
  float* ps   = pm + (size_t)BB * KK * JJ;

  span_pool_a<<<dim3(BB * KK, JJ), dim3(256), 0, stream>>>(
      th, attn, sps, spe, wp, pacc, pm, ps);
  span_pool_b<<<dim3(BB * KK), dim3(192), 0, stream>>>(
      pacc, pm, ps, Hout, sent);
}

// Round 3
// 173.120 us; speedup vs baseline: 1.0127x; 1.0127x over previous
//
#include <hip/hip_runtime.h>

#define BB 16
#define LL 2048
#define DD 768
#define KK 32
#define NEGI -1e30f
#define JJ 8                 // sub-blocks per span in the weighted-sum pass
#define AW 4                 // waves per block
#define SLOTS (JJ * AW)      // 32 row-slots per span

// ---------------------------------------------------------------------------
// Pass 1: scores[b,l] = dot(th[b,l,:], w).  One wave per row, 4 rows/block.
// The 6-hop shuffle reduce is fine HERE because there are 32768 independent
// rows (32 waves/CU of TLP hides all latency). Pure 96 MB HBM stream.
// R2 post-mortem: the fused kernel was latency-serialized (59 us, 10% BW,
// 4.5% VALUBusy) because the per-row chain [loads -> dot -> 6 serial
// shuffles -> uniform branch -> exp -> carried (m,s,acc)] cannot pipeline.
// Precomputing scores removes every cross-lane/carried dependency from the
// heavy pass.
// ---------------------------------------------------------------------------
__global__ __launch_bounds__(256) void span_scores(
    const float* __restrict__ th,
    const float* __restrict__ wp,
    float* __restrict__ scores) {       // [B*L]
  const int row  = blockIdx.x * 4 + (threadIdx.x >> 6);  // 0 .. B*L-1
  const int lane = threadIdx.x & 63;

  const float4* wr = (const float4*)wp;
  const float4 w0 = wr[lane], w1 = wr[lane + 64], w2 = wr[lane + 128];

  const float4* r = (const float4*)(th + (size_t)row * DD);
  float4 r0 = r[lane], r1 = r[lane + 64], r2 = r[lane + 128];

  float d = 0.f;
  d = fmaf(r0.x, w0.x, d); d = fmaf(r0.y, w0.y, d);
  d = fmaf(r0.z, w0.z, d); d = fmaf(r0.w, w0.w, d);
  d = fmaf(r1.x, w1.x, d); d = fmaf(r1.y, w1.y, d);
  d = fmaf(r1.z, w1.z, d); d = fmaf(r1.w, w1.w, d);
  d = fmaf(r2.x, w2.x, d); d = fmaf(r2.y, w2.y, d);
  d = fmaf(r2.z, w2.z, d); d = fmaf(r2.w, w2.w, d);
  #pragma unroll
  for (int o = 32; o > 0; o >>= 1) d += __shfl_xor(d, o, 64);

  if (lane == 0) scores[row] = d;  // b_pool dropped: softmax shift-invariant
}

// ---------------------------------------------------------------------------
// Pass 2: grid (B*K, J). Per block: (a) block-reduce span max M and sumexp S
// over the span's scores (<=2 KB, L2-hot; duplicated across J blocks, cheap
// and fully parallel); (b) weighted partial sum over rows l = s0+slot+i*32:
//   e = (attn>=0.5) ? exp(sc[l]-M) : 0;  acc += e * row
// No shuffles, no branches, no loop-carried scalar state -> the row loads
// pipeline freely (th is L3-warm from pass 1). All J partials share the same
// (M,S) normalization, so the final merge is a plain sum.
// ---------------------------------------------------------------------------
__global__ __launch_bounds__(256) void span_wsum(
    const float* __restrict__ th,
    const float* __restrict__ attn,
    const float* __restrict__ scores,
    const int* __restrict__ sps,
    const int* __restrict__ spe,
    float* __restrict__ pacc,    // [B*K, J, 768] partial sums (shared norm)
    float* __restrict__ sspan) { // [B*K] softmax denominator S
  const int bk = blockIdx.x;
  const int j  = blockIdx.y;
  const int b  = bk >> 5;             // K = 32
  const int t    = threadIdx.x;
  const int lane = t & 63;
  const int wave = t >> 6;
  const int slot = j * AW + wave;     // 0..31

  __shared__ float sacc[AW][DD];      // 12 KB wave partials
  __shared__ float redm[AW], reds[AW];

  const int s0 = min(max(sps[bk], 0), LL);
  const int e0 = min(max(spe[bk], 0), LL);

  const float* sc   = scores + (size_t)b * LL;
  const float* arow = attn + (size_t)b * LL;
  const float4* tb  = (const float4*)(th + (size_t)b * LL * DD);

  // ---- phase A: span max ----
  float lm = NEGI;
  for (int l = s0 + t; l < e0; l += 256)
    if (arow[l] >= 0.5f) lm = fmaxf(lm, sc[l]);
  #pragma unroll
  for (int o = 32; o > 0; o >>= 1) lm = fmaxf(lm, __shfl_xor(lm, o, 64));
  if (lane == 0) redm[wave] = lm;
  __syncthreads();
  const float M = fmaxf(fmaxf(redm[0], redm[1]), fmaxf(redm[2], redm[3]));

  // ---- phase A: span sumexp (masked rows skipped -> no inf even if M=NEGI)
  float ls = 0.f;
  for (int l = s0 + t; l < e0; l += 256)
    if (arow[l] >= 0.5f) ls += __expf(sc[l] - M);
  #pragma unroll
  for (int o = 32; o > 0; o >>= 1) ls += __shfl_xor(ls, o, 64);
  if (lane == 0) reds[wave] = ls;
  __syncthreads();
  const float S = reds[0] + reds[1] + reds[2] + reds[3];
  if (j == 0 && t == 0) sspan[bk] = S;  // identical across j; one writer

  // ---- phase B: weighted partial sum, fully pipelineable ----
  float4 a0 = make_float4(0.f, 0.f, 0.f, 0.f), a1 = a0, a2 = a0;
  #pragma unroll 4
  for (int l = s0 + slot; l < e0; l += SLOTS) {
    const float4* row = tb + (size_t)l * (DD / 4);
    float4 r0 = row[lane], r1 = row[lane + 64], r2 = row[lane + 128];
    float e = __expf(sc[l] - M);        // finite when span has a valid row
    e = (arow[l] >= 0.5f) ? e : 0.f;    // masked (or all-masked inf) -> 0
    a0.x = fmaf(e, r0.x, a0.x); a0.y = fmaf(e, r0.y, a0.y);
    a0.z = fmaf(e, r0.z, a0.z); a0.w = fmaf(e, r0.w, a0.w);
    a1.x = fmaf(e, r1.x, a1.x); a1.y = fmaf(e, r1.y, a1.y);
    a1.z = fmaf(e, r1.z, a1.z); a1.w = fmaf(e, r1.w, a1.w);
    a2.x = fmaf(e, r2.x, a2.x); a2.y = fmaf(e, r2.y, a2.y);
    a2.z = fmaf(e, r2.z, a2.z); a2.w = fmaf(e, r2.w, a2.w);
  }

  // ---- merge 4 wave partials (plain sum; same normalization) ----
  float4* sa = (float4*)sacc[wave];
  sa[lane] = a0; sa[lane + 64] = a1; sa[lane + 128] = a2;
  __syncthreads();
  if (t < DD / 4) {
    float4 o = make_float4(0.f, 0.f, 0.f, 0.f);
    #pragma unroll
    for (int w = 0; w < AW; ++w) {
      const float4 p = ((const float4*)sacc[w])[t];
      o.x += p.x; o.y += p.y; o.z += p.z; o.w += p.w;
    }
    // always written: workspace is poisoned between iterations
    ((float4*)(pacc + (size_t)(bk * JJ + j) * DD))[t] = o;
  }
}

// ---------------------------------------------------------------------------
// Pass 3: sum the J partials (12.6 MB, L2/L3-warm), normalize, write H+sent.
// ---------------------------------------------------------------------------
__global__ __launch_bounds__(192) void span_merge(
    const float* __restrict__ pacc,
    const float* __restrict__ sspan,
    float* __restrict__ Hout,
    float* __restrict__ sent) {
  const int bk = blockIdx.x;
  const int t = threadIdx.x;  // 0..191, one float4 of the 768 dims

  const float S = sspan[bk];
  const float inv = (S > 0.f) ? (1.0f / S) : 0.f;  // empty/all-masked -> 0

  float4 o = make_float4(0.f, 0.f, 0.f, 0.f);
  #pragma unroll
  for (int jv = 0; jv < JJ; ++jv) {
    const float4 p = ((const float4*)(pacc + (size_t)(bk * JJ + jv) * DD))[t];
    o.x += p.x; o.y += p.y; o.z += p.z; o.w += p.w;
  }
  o.x *= inv; o.y *= inv; o.z *= inv; o.w *= inv;
  ((float4*)(Hout + (size_t)bk * DD))[t] = o;  // all 768 dims always written
  if (t == 0) sent[bk] = (S > 0.f) ? 1.0f : 0.0f;
}

extern "C" void kernel_launch(void* const* d_in, const int* in_sizes, int n_in,
                              void* d_out, int out_size, void* d_ws, size_t ws_size,
                              hipStream_t stream) {
  const float* th   = (const float*)d_in[0];  // [B,L,D] fp32
  const float* attn = (const float*)d_in[1];  // [B,L]   fp32
  const int*   sps  = (const int*)d_in[2];    // [B,K]
  const int*   spe  = (const int*)d_in[3];    // [B,K]
  const float* wp   = (const float*)d_in[4];  // [D]     fp32
  // d_in[5] (b_pool) intentionally unused: softmax(x + c) == softmax(x)

  float* Hout = (float*)d_out;                 // [B,K,D] then sent [B,K]
  float* sent = Hout + (size_t)BB * KK * DD;

  // workspace: scores 512 KB + pacc 12.6 MB + sspan 2 KB  (ws is ~384 MB)
  float* scores = (float*)d_ws;
  float* pacc   = scores + (size_t)BB * LL;
  float* sspan  = pacc + (size_t)BB * KK * JJ * DD;

  span_scores<<<dim3(BB * LL / 4), dim3(256), 0, stream>>>(th, wp, scores);
  span_wsum<<<dim3(BB * KK, JJ), dim3(256), 0, stream>>>(
      th, attn, scores, sps, spe, pacc, sspan);
  span_merge<<<dim3(BB * KK), dim3(192), 0, stream>>>(
      pacc, sspan, Hout, sent);
}